// Round 17
// baseline (230.081 us; speedup 1.0000x reference)
//
#include <hip/hip_runtime.h>

typedef __attribute__((ext_vector_type(8))) short short8;
typedef __attribute__((ext_vector_type(4))) float f32x4;

#define M_ROWS (512*512)
#define NTILES (M_ROWS/64)
#define GRID_SETUP 512
#define GRID_STATS 512
#define GRID_MLP 256
#define ROWS_MLP (M_ROWS/GRID_MLP)   // 1024
#define TILES_MLP (ROWS_MLP/64)      // 16
#define BN_EPS_F 1e-5f

// ws layout in float units
#define WS_P1   64        // 512 blocks * 24 floats (layer1 stat partials)
#define WS_CNT  12352
#define WS_A1   12416     // 4*256 folded W1*a1
#define WS_D1   13440     // 256
#define WS_A2   13696     // 256
#define WS_C2   13952     // 256
#define WS_W2T  14336     // ushort[65536] (W2^T bf16 [n][k])
#define WS_W3T  47104     // ushort[65536]
#define WS_P2   79872     // 512 blocks * 512 floats (layer2 BN partials)

__device__ __forceinline__ float load_mask(const void* mp, int fmt, int row) {
  return fmt ? (((const unsigned char*)mp)[row] ? 1.f : 0.f)
             : (((const int*)mp)[row] ? 1.f : 0.f);
}

__device__ __forceinline__ ushort f2bf(float f) {
  unsigned int u = __float_as_uint(f);
  u += 0x7FFFu + ((u >> 16) & 1u);   // RNE
  return (ushort)(u >> 16);
}

// LDS-only barrier: does NOT drain vmcnt, so global stores stay in flight.
__device__ __forceinline__ void barrier_lds() {
  __builtin_amdgcn_sched_barrier(0);
  asm volatile("s_waitcnt lgkmcnt(0)");
  __builtin_amdgcn_sched_barrier(0);
  __builtin_amdgcn_s_barrier();
  __builtin_amdgcn_sched_barrier(0);
}

// 256-thread h1: thread handles 2 cols x 32 rows (bf16, swizzled [64][256]).
__device__ __forceinline__ void compute_h1(
    const float (*xs)[4], ushort* h1s, int t,
    const float a1c[4][2], const float d1c[2]) {
  const int c0 = (t & 127) * 2;
  const int r0 = (t >> 7) * 32;
  #pragma unroll 4
  for (int rr = 0; rr < 32; ++rr) {
    const int r = r0 + rr;
    const f32x4 xv = *(const f32x4*)&xs[r][0];
    float v0 = d1c[0], v1 = d1c[1];
    v0 = fmaf(xv.x, a1c[0][0], v0); v1 = fmaf(xv.x, a1c[0][1], v1);
    v0 = fmaf(xv.y, a1c[1][0], v0); v1 = fmaf(xv.y, a1c[1][1], v1);
    v0 = fmaf(xv.z, a1c[2][0], v0); v1 = fmaf(xv.z, a1c[2][1], v1);
    v0 = fmaf(xv.w, a1c[3][0], v0); v1 = fmaf(xv.w, a1c[3][1], v1);
    v0 = fmaxf(v0, 0.f); v1 = fmaxf(v1, 0.f);
    unsigned int pk = (unsigned int)f2bf(v0) | ((unsigned int)f2bf(v1) << 16);
    unsigned int byte = (unsigned int)r*512u + (unsigned int)c0*2u;
    byte ^= (unsigned int)(r & 7) << 4;
    *(unsigned int*)((char*)h1s + byte) = pk;
  }
}

__device__ __forceinline__ void load_aF(const ushort* h1s, int lane, int ks,
                                        int kb, short8 aF[4]) {
  #pragma unroll
  for (int rf = 0; rf < 4; ++rf) {
    const int row = rf*16 + (lane & 15);
    unsigned int byte = (unsigned int)row*512u + (unsigned int)((ks*32 + kb)*2);
    byte ^= (unsigned int)(row & 7) << 4;
    aF[rf] = *(const short8*)((const char*)h1s + byte);
  }
}

// wave owns 64 cols (4 col-fragments)
__device__ __forceinline__ void gemm_reg(const ushort* h1s,
    const short8 Br[4][8], int lane, f32x4 acc[4][4]) {
  const int kb = (lane >> 4) * 8;
  #pragma unroll
  for (int ks = 0; ks < 8; ++ks) {
    short8 aF[4];
    load_aF(h1s, lane, ks, kb, aF);
    #pragma unroll
    for (int cf = 0; cf < 4; ++cf)
      #pragma unroll
      for (int rf = 0; rf < 4; ++rf)
        acc[rf][cf] = __builtin_amdgcn_mfma_f32_16x16x32_bf16(
            aF[rf], Br[cf][ks], acc[rf][cf], 0, 0, 0);
  }
}

__device__ __forceinline__ void load_B(const ushort* __restrict__ Wt,
                                       int lane, int wave, short8 Br[4][8]) {
  const int kb = (lane >> 4) * 8;
  const ushort* wp = Wt + (size_t)(wave*64 + (lane & 15))*256 + kb;
  #pragma unroll
  for (int cf = 0; cf < 4; ++cf)
    #pragma unroll
    for (int ks = 0; ks < 8; ++ks)
      Br[cf][ks] = *(const short8*)(wp + cf*4096 + ks*32);
}

// ---- setup: per-block mask-detect + layer1 stat partials + W row convert ----
__global__ __launch_bounds__(256) void setup_kernel(
    const float* __restrict__ bbox, const void* __restrict__ maskp,
    const float* __restrict__ W2, const float* __restrict__ W3,
    float* __restrict__ wsf) {
  __shared__ int s_fmt;
  __shared__ float red[256][22];
  const int t = threadIdx.x, b = blockIdx.x;
  if (t == 0) s_fmt = 0;
  __syncthreads();
  {
    const uint4 v = ((const uint4*)maskp)[t];  // first 4 KB, always in-bounds
    if (((v.x | v.y | v.z | v.w) & 0xFFFFFF00u) != 0u) s_fmt = 1;
  }
  __syncthreads();
  const int fmt = s_fmt;

  float own[21];
  #pragma unroll
  for (int i = 0; i < 21; ++i) own[i] = 0.f;
  #pragma unroll
  for (int i = 0; i < 2; ++i) {
    const int row = b*512 + i*256 + t;
    const float m = load_mask(maskp, fmt, row);
    if (m != 0.f) {
      float4 x4 = *(const float4*)(bbox + (size_t)row * 16);
      float xv[4] = {x4.x, x4.y, x4.z, x4.w};
      own[0] += 1.f;
      #pragma unroll
      for (int i2 = 0; i2 < 4; ++i2) {
        own[1+i2] += xv[i2];
        #pragma unroll
        for (int j = 0; j < 4; ++j)
          own[5+i2*4+j] = fmaf(xv[i2], xv[j], own[5+i2*4+j]);
      }
    }
  }
  #pragma unroll
  for (int s = 0; s < 21; ++s) red[t][s] = own[s];
  __syncthreads();
  for (int off = 128; off > 0; off >>= 1) {
    if (t < off) {
      #pragma unroll
      for (int s = 0; s < 21; ++s) red[t][s] += red[t+off][s];
    }
    __syncthreads();
  }
  if (t < 21) wsf[WS_P1 + b*24 + t] = red[0][t];

  // one k-row of W2 (blocks 0-255) / W3 (blocks 256-511) -> bf16 transposed
  if (b < 256) {
    ((ushort*)(wsf + WS_W2T))[t*256 + b] = f2bf(W2[b*256 + t]);
  } else {
    const int bb = b - 256;
    ((ushort*)(wsf + WS_W3T))[t*256 + bb] = f2bf(W3[bb*256 + t]);
  }
}

// ---- finalize1: parallel reduce of 512 partials + layer-1 BN fold ----
__global__ __launch_bounds__(256) void finalize1_kernel(
    const float* __restrict__ part, const float* __restrict__ W1,
    const float* __restrict__ b1, const float* __restrict__ g1,
    const float* __restrict__ be1, float* __restrict__ wsf) {
  __shared__ float red[256][22];
  __shared__ float sarr[21];
  const int t = threadIdx.x;
  #pragma unroll
  for (int s = 0; s < 21; ++s)
    red[t][s] = part[t*24 + s] + part[(t+256)*24 + s];
  __syncthreads();
  for (int off = 128; off > 0; off >>= 1) {
    if (t < off) {
      #pragma unroll
      for (int s = 0; s < 21; ++s) red[t][s] += red[t+off][s];
    }
    __syncthreads();
  }
  if (t < 21) sarr[t] = red[0][t];
  __syncthreads();
  float s[21];
  #pragma unroll
  for (int i = 0; i < 21; ++i) s[i] = sarr[i];
  const float cnt = fmaxf(s[0], 1.f);
  float w[4] = {W1[t], W1[256+t], W1[512+t], W1[768+t]};
  const float b1f = b1[t];
  float sw = 0.f;
  #pragma unroll
  for (int k = 0; k < 4; ++k) sw = fmaf(s[1+k], w[k], sw);
  float qf = 0.f;
  #pragma unroll
  for (int i = 0; i < 4; ++i)
    #pragma unroll
    for (int j = 0; j < 4; ++j) qf = fmaf(s[5+i*4+j]*w[i], w[j], qf);
  const float mu  = sw/cnt + b1f;
  const float eh2 = (qf + 2.f*b1f*sw)/cnt + b1f*b1f;
  const float var = fmaxf(eh2 - mu*mu, 0.f);
  const float a1  = g1[t] * rsqrtf(var + BN_EPS_F);
  const float c1  = be1[t] - mu*a1;
  #pragma unroll
  for (int k = 0; k < 4; ++k) wsf[WS_A1 + k*256 + t] = w[k]*a1;
  wsf[WS_D1 + t] = fmaf(b1f, a1, c1);
  if (t == 0) wsf[WS_CNT] = cnt;
}

// ---- stats2: h1 -> GEMM2 (B2 regs) -> masked sum/sq partials (2 w/SIMD) ----
__global__ __launch_bounds__(256, 2) void stats2_mfma(
    const float* __restrict__ bbox, const void* __restrict__ maskp,
    const float* wsf, const float* __restrict__ b2,
    float* __restrict__ part2) {
  __shared__ float xs[64][4];
  __shared__ float ms[64];
  __shared__ ushort h1s[64*256];
  __shared__ int s_fmt;
  const int t = threadIdx.x, lane = t & 63, wave = t >> 6;
  if (t == 0) s_fmt = 0;
  __syncthreads();
  {
    const uint4 v = ((const uint4*)maskp)[t];
    if (((v.x | v.y | v.z | v.w) & 0xFFFFFF00u) != 0u) s_fmt = 1;
  }
  __syncthreads();
  const int fmt = s_fmt;
  float a1c[4][2], d1c[2];
  {
    const int c0 = (t & 127) * 2;
    #pragma unroll
    for (int j = 0; j < 4; ++j) {
      a1c[j][0] = wsf[WS_A1 + j*256 + c0];
      a1c[j][1] = wsf[WS_A1 + j*256 + c0 + 1];
    }
    d1c[0] = wsf[WS_D1 + c0]; d1c[1] = wsf[WS_D1 + c0 + 1];
  }
  short8 B2r[4][8];
  load_B((const ushort*)(wsf + WS_W2T), lane, wave, B2r);
  float b2v[4];
  #pragma unroll
  for (int cf = 0; cf < 4; ++cf) b2v[cf] = b2[wave*64 + cf*16 + (lane & 15)];
  float pS[4] = {0,0,0,0}, pQ[4] = {0,0,0,0};

  for (int tile = blockIdx.x; tile < NTILES; tile += GRID_STATS) {
    const int row0 = tile << 6;
    __syncthreads();
    if (t < 64) {
      float4 x4 = *(const float4*)(bbox + (size_t)(row0 + t) * 16);
      xs[t][0] = x4.x; xs[t][1] = x4.y; xs[t][2] = x4.z; xs[t][3] = x4.w;
      ms[t] = load_mask(maskp, fmt, row0 + t);
    }
    __syncthreads();
    compute_h1(xs, h1s, t, a1c, d1c);
    __syncthreads();
    f32x4 acc[4][4];
    #pragma unroll
    for (int rf = 0; rf < 4; ++rf)
      #pragma unroll
      for (int cf = 0; cf < 4; ++cf)
        acc[rf][cf] = (f32x4){b2v[cf], b2v[cf], b2v[cf], b2v[cf]};
    gemm_reg(h1s, B2r, lane, acc);
    float mr[4][4];
    #pragma unroll
    for (int rf = 0; rf < 4; ++rf)
      #pragma unroll
      for (int r = 0; r < 4; ++r)
        mr[rf][r] = ms[rf*16 + ((lane >> 4) * 4) + r];
    #pragma unroll
    for (int cf = 0; cf < 4; ++cf)
      #pragma unroll
      for (int rf = 0; rf < 4; ++rf)
        #pragma unroll
        for (int r = 0; r < 4; ++r) {
          const float m = mr[rf][r];
          const float v = acc[rf][cf][r];
          pS[cf] = fmaf(m, v, pS[cf]);
          pQ[cf] = fmaf(m*v, v, pQ[cf]);
        }
  }
  #pragma unroll
  for (int cf = 0; cf < 4; ++cf) {
    pS[cf] += __shfl_xor(pS[cf], 16); pS[cf] += __shfl_xor(pS[cf], 32);
    pQ[cf] += __shfl_xor(pQ[cf], 16); pQ[cf] += __shfl_xor(pQ[cf], 32);
  }
  if (lane < 16) {
    #pragma unroll
    for (int cf = 0; cf < 4; ++cf) {
      const int col = wave*64 + cf*16 + lane;
      part2[(size_t)blockIdx.x*512 + col] = pS[cf];
      part2[(size_t)blockIdx.x*512 + 256 + col] = pQ[cf];
    }
  }
}

// ---- finalize2: one block per feature -> a2/c2 ----
__global__ __launch_bounds__(256) void finalize2_kernel(
    float* __restrict__ wsf, const float* __restrict__ g2,
    const float* __restrict__ be2) {
  const int f = blockIdx.x, t = threadIdx.x;
  const float* part2 = wsf + WS_P2;
  float s1 = 0.f, s2 = 0.f;
  for (int b = t; b < GRID_STATS; b += 256) {
    s1 += part2[(size_t)b*512 + f];
    s2 += part2[(size_t)b*512 + 256 + f];
  }
  __shared__ float r1[256], r2[256];
  r1[t] = s1; r2[t] = s2;
  __syncthreads();
  for (int off = 128; off > 0; off >>= 1) {
    if (t < off) { r1[t] += r1[t+off]; r2[t] += r2[t+off]; }
    __syncthreads();
  }
  if (t == 0) {
    const float cnt = wsf[WS_CNT];
    const float mu  = r1[0]/cnt;
    const float var = fmaxf(r2[0]/cnt - mu*mu, 0.f);
    const float a2  = g2[f] * rsqrtf(var + BN_EPS_F);
    wsf[WS_A2 + f] = a2;
    wsf[WS_C2 + f] = be2[f] - mu*a2;
  }
}

// ---- mlp3: r10 structure + separate h2 LDS buffer -> 2 barriers/tile
// (was 4). Safety: (B1) h1 visible before GEMM2; (B2) h2 visible before
// GEMM3 AND all GEMM2 h1-reads done before any next-tile h1 write (those
// writes sit behind this B2); tile+1's h2 writes sit behind tile+1's B1,
// which no wave reaches until all waves finish tile's GEMM3 h2-reads.
// GEMM3+stores now overlap next tile's h1 VALU with no barrier between. ----
__global__ __launch_bounds__(256, 1) void mlp3_mfma(
    const float* __restrict__ bbox, const void* __restrict__ maskp,
    const float* wsf, const float* __restrict__ b2,
    const float* __restrict__ b3, float* __restrict__ out) {
  __shared__ ushort h1s[64*256];       // 32 KB
  __shared__ ushort h2s[64*256];       // 32 KB
  __shared__ float xst[ROWS_MLP][4];   // 16 KB
  __shared__ float mst[ROWS_MLP];      // 4 KB
  __shared__ int s_fmt;
  const int t = threadIdx.x, lane = t & 63, wave = t >> 6;
  if (t == 0) s_fmt = 0;
  __syncthreads();
  {
    const uint4 v = ((const uint4*)maskp)[t];
    if (((v.x | v.y | v.z | v.w) & 0xFFFFFF00u) != 0u) s_fmt = 1;
  }
  __syncthreads();
  const int fmt = s_fmt;
  const int row_base = blockIdx.x * ROWS_MLP;

  #pragma unroll
  for (int i = 0; i < ROWS_MLP/256; ++i) {
    const int r = i*256 + t;
    float4 x4 = *(const float4*)(bbox + (size_t)(row_base + r) * 16);
    xst[r][0] = x4.x; xst[r][1] = x4.y; xst[r][2] = x4.z; xst[r][3] = x4.w;
    mst[r] = load_mask(maskp, fmt, row_base + r);
  }
  float a1c[4][2], d1c[2];
  {
    const int c0 = (t & 127) * 2;
    #pragma unroll
    for (int j = 0; j < 4; ++j) {
      a1c[j][0] = wsf[WS_A1 + j*256 + c0];
      a1c[j][1] = wsf[WS_A1 + j*256 + c0 + 1];
    }
    d1c[0] = wsf[WS_D1 + c0]; d1c[1] = wsf[WS_D1 + c0 + 1];
  }
  short8 B2r[4][8], B3r[4][8];
  load_B((const ushort*)(wsf + WS_W2T), lane, wave, B2r);
  load_B((const ushort*)(wsf + WS_W3T), lane, wave, B3r);
  float b2v[4], b3v[4], a2v[4], c2v[4];
  #pragma unroll
  for (int cf = 0; cf < 4; ++cf) {
    const int col = wave*64 + cf*16 + (lane & 15);
    b2v[cf] = b2[col]; b3v[cf] = b3[col];
    a2v[cf] = wsf[WS_A2 + col]; c2v[cf] = wsf[WS_C2 + col];
  }
  __syncthreads();

  for (int tile = 0; tile < TILES_MLP; ++tile) {
    const int r0 = tile * 64;
    compute_h1(&xst[r0], h1s, t, a1c, d1c);
    barrier_lds();   // B1: h1 visible
    f32x4 acc[4][4];
    #pragma unroll
    for (int rf = 0; rf < 4; ++rf)
      #pragma unroll
      for (int cf = 0; cf < 4; ++cf)
        acc[rf][cf] = (f32x4){b2v[cf], b2v[cf], b2v[cf], b2v[cf]};
    gemm_reg(h1s, B2r, lane, acc);
    // BN2 + ReLU -> h2s (separate buffer: no hazard vs h1s reads)
    #pragma unroll
    for (int rf = 0; rf < 4; ++rf)
      #pragma unroll
      for (int cf = 0; cf < 4; ++cf) {
        const int col = wave*64 + cf*16 + (lane & 15);
        #pragma unroll
        for (int r = 0; r < 4; ++r) {
          const float v = fmaxf(fmaf(acc[rf][cf][r], a2v[cf], c2v[cf]), 0.f);
          const int row = rf*16 + ((lane >> 4) * 4) + r;
          unsigned int byte = (unsigned int)row*512u + (unsigned int)col*2u;
          byte ^= (unsigned int)(row & 7) << 4;
          *(ushort*)((char*)h2s + byte) = f2bf(v);
        }
      }
    barrier_lds();   // B2: h2 visible (and all h1 reads complete)
    #pragma unroll
    for (int rf = 0; rf < 4; ++rf)
      #pragma unroll
      for (int cf = 0; cf < 4; ++cf)
        acc[rf][cf] = (f32x4){b3v[cf], b3v[cf], b3v[cf], b3v[cf]};
    gemm_reg(h2s, B3r, lane, acc);
    float mr[4][4];
    #pragma unroll
    for (int rf = 0; rf < 4; ++rf)
      #pragma unroll
      for (int r = 0; r < 4; ++r)
        mr[rf][r] = mst[r0 + rf*16 + ((lane >> 4) * 4) + r];
    #pragma unroll
    for (int rf = 0; rf < 4; ++rf)
      #pragma unroll
      for (int cf = 0; cf < 4; ++cf) {
        const int col = wave*64 + cf*16 + (lane & 15);
        #pragma unroll
        for (int r = 0; r < 4; ++r) {
          const int lrow = rf*16 + ((lane >> 4) * 4) + r;
          out[(size_t)(row_base + r0 + lrow)*256 + col] =
              acc[rf][cf][r] * mr[rf][r];
        }
      }
    // no barrier: next tile's h1 writes are safe (gemm2 reads drained at B2;
    // h2s reads here are protected by next tile's B1)
  }
}

extern "C" void kernel_launch(void* const* d_in, const int* in_sizes, int n_in,
                              void* d_out, int out_size, void* d_ws, size_t ws_size,
                              hipStream_t stream) {
  (void)in_sizes; (void)n_in; (void)out_size; (void)ws_size;
  const float* bbox = (const float*)d_in[0];
  const void*  maskp= d_in[1];
  const float* W1 = (const float*)d_in[2];
  const float* b1 = (const float*)d_in[3];
  const float* g1 = (const float*)d_in[4];
  const float* be1= (const float*)d_in[5];
  const float* W2 = (const float*)d_in[6];
  const float* b2 = (const float*)d_in[7];
  const float* g2 = (const float*)d_in[8];
  const float* be2= (const float*)d_in[9];
  const float* W3 = (const float*)d_in[10];
  const float* b3 = (const float*)d_in[11];
  float* out = (float*)d_out;
  float* wsf = (float*)d_ws;

  hipLaunchKernelGGL(setup_kernel, dim3(GRID_SETUP), dim3(256), 0, stream,
                     bbox, maskp, W2, W3, wsf);
  hipLaunchKernelGGL(finalize1_kernel, dim3(1), dim3(256), 0, stream,
                     wsf + WS_P1, W1, b1, g1, be1, wsf);
  hipLaunchKernelGGL(stats2_mfma, dim3(GRID_STATS), dim3(256), 0, stream,
                     bbox, maskp, wsf, b2, wsf + WS_P2);
  hipLaunchKernelGGL(finalize2_kernel, dim3(256), dim3(256), 0, stream,
                     wsf, g2, be2);
  hipLaunchKernelGGL(mlp3_mfma, dim3(GRID_MLP), dim3(256), 0, stream,
                     bbox, maskp, wsf, b2, b3, out);
}

// Round 18
// 205.326 us; speedup vs baseline: 1.1206x; 1.1206x over previous
//
#include <hip/hip_runtime.h>

typedef __attribute__((ext_vector_type(8))) short short8;
typedef __attribute__((ext_vector_type(4))) float f32x4;

#define M_ROWS (512*512)
#define NTILES (M_ROWS/64)
#define GRID_SETUP 512
#define GRID_STATS 512
#define GRID_MLP 256
#define ROWS_MLP (M_ROWS/GRID_MLP)   // 1024
#define TILES_MLP (ROWS_MLP/64)      // 16
#define BN_EPS_F 1e-5f

// ws layout in float units
#define WS_P1   64        // 512 blocks * 24 floats (layer1 stat partials)
#define WS_CNT  12352
#define WS_A1   12416     // 4*256 folded W1*a1
#define WS_D1   13440     // 256
#define WS_A2   13696     // 256
#define WS_C2   13952     // 256
#define WS_W2T  14336     // ushort[65536] (W2^T bf16 [n][k])
#define WS_W3T  47104     // ushort[65536]
#define WS_P2   79872     // 512 blocks * 512 floats (layer2 BN partials)

__device__ __forceinline__ float load_mask(const void* mp, int fmt, int row) {
  return fmt ? (((const unsigned char*)mp)[row] ? 1.f : 0.f)
             : (((const int*)mp)[row] ? 1.f : 0.f);
}

__device__ __forceinline__ ushort f2bf(float f) {
  unsigned int u = __float_as_uint(f);
  u += 0x7FFFu + ((u >> 16) & 1u);   // RNE
  return (ushort)(u >> 16);
}

// LDS-only barrier: does NOT drain vmcnt, so global stores stay in flight.
__device__ __forceinline__ void barrier_lds() {
  __builtin_amdgcn_sched_barrier(0);
  asm volatile("s_waitcnt lgkmcnt(0)");
  __builtin_amdgcn_sched_barrier(0);
  __builtin_amdgcn_s_barrier();
  __builtin_amdgcn_sched_barrier(0);
}

// 256-thread h1: thread handles 2 cols x 32 rows (bf16, swizzled [64][256]).
__device__ __forceinline__ void compute_h1(
    const float (*xs)[4], ushort* h1s, int t,
    const float a1c[4][2], const float d1c[2]) {
  const int c0 = (t & 127) * 2;
  const int r0 = (t >> 7) * 32;
  #pragma unroll 4
  for (int rr = 0; rr < 32; ++rr) {
    const int r = r0 + rr;
    const f32x4 xv = *(const f32x4*)&xs[r][0];
    float v0 = d1c[0], v1 = d1c[1];
    v0 = fmaf(xv.x, a1c[0][0], v0); v1 = fmaf(xv.x, a1c[0][1], v1);
    v0 = fmaf(xv.y, a1c[1][0], v0); v1 = fmaf(xv.y, a1c[1][1], v1);
    v0 = fmaf(xv.z, a1c[2][0], v0); v1 = fmaf(xv.z, a1c[2][1], v1);
    v0 = fmaf(xv.w, a1c[3][0], v0); v1 = fmaf(xv.w, a1c[3][1], v1);
    v0 = fmaxf(v0, 0.f); v1 = fmaxf(v1, 0.f);
    unsigned int pk = (unsigned int)f2bf(v0) | ((unsigned int)f2bf(v1) << 16);
    unsigned int byte = (unsigned int)r*512u + (unsigned int)c0*2u;
    byte ^= (unsigned int)(r & 7) << 4;
    *(unsigned int*)((char*)h1s + byte) = pk;
  }
}

__device__ __forceinline__ void load_aF(const ushort* h1s, int lane, int ks,
                                        int kb, short8 aF[4]) {
  #pragma unroll
  for (int rf = 0; rf < 4; ++rf) {
    const int row = rf*16 + (lane & 15);
    unsigned int byte = (unsigned int)row*512u + (unsigned int)((ks*32 + kb)*2);
    byte ^= (unsigned int)(row & 7) << 4;
    aF[rf] = *(const short8*)((const char*)h1s + byte);
  }
}

// wave owns 64 cols (4 col-fragments)
__device__ __forceinline__ void gemm_reg(const ushort* h1s,
    const short8 Br[4][8], int lane, f32x4 acc[4][4]) {
  const int kb = (lane >> 4) * 8;
  #pragma unroll
  for (int ks = 0; ks < 8; ++ks) {
    short8 aF[4];
    load_aF(h1s, lane, ks, kb, aF);
    #pragma unroll
    for (int cf = 0; cf < 4; ++cf)
      #pragma unroll
      for (int rf = 0; rf < 4; ++rf)
        acc[rf][cf] = __builtin_amdgcn_mfma_f32_16x16x32_bf16(
            aF[rf], Br[cf][ks], acc[rf][cf], 0, 0, 0);
  }
}

__device__ __forceinline__ void load_B(const ushort* __restrict__ Wt,
                                       int lane, int wave, short8 Br[4][8]) {
  const int kb = (lane >> 4) * 8;
  const ushort* wp = Wt + (size_t)(wave*64 + (lane & 15))*256 + kb;
  #pragma unroll
  for (int cf = 0; cf < 4; ++cf)
    #pragma unroll
    for (int ks = 0; ks < 8; ++ks)
      Br[cf][ks] = *(const short8*)(wp + cf*4096 + ks*32);
}

// ---- setup: per-block mask-detect + layer1 stat partials + W row convert ----
__global__ __launch_bounds__(256) void setup_kernel(
    const float* __restrict__ bbox, const void* __restrict__ maskp,
    const float* __restrict__ W2, const float* __restrict__ W3,
    float* __restrict__ wsf) {
  __shared__ int s_fmt;
  __shared__ float red[256][22];
  const int t = threadIdx.x, b = blockIdx.x;
  if (t == 0) s_fmt = 0;
  __syncthreads();
  {
    const uint4 v = ((const uint4*)maskp)[t];  // first 4 KB, always in-bounds
    if (((v.x | v.y | v.z | v.w) & 0xFFFFFF00u) != 0u) s_fmt = 1;
  }
  __syncthreads();
  const int fmt = s_fmt;

  float own[21];
  #pragma unroll
  for (int i = 0; i < 21; ++i) own[i] = 0.f;
  #pragma unroll
  for (int i = 0; i < 2; ++i) {
    const int row = b*512 + i*256 + t;
    const float m = load_mask(maskp, fmt, row);
    if (m != 0.f) {
      float4 x4 = *(const float4*)(bbox + (size_t)row * 16);
      float xv[4] = {x4.x, x4.y, x4.z, x4.w};
      own[0] += 1.f;
      #pragma unroll
      for (int i2 = 0; i2 < 4; ++i2) {
        own[1+i2] += xv[i2];
        #pragma unroll
        for (int j = 0; j < 4; ++j)
          own[5+i2*4+j] = fmaf(xv[i2], xv[j], own[5+i2*4+j]);
      }
    }
  }
  #pragma unroll
  for (int s = 0; s < 21; ++s) red[t][s] = own[s];
  __syncthreads();
  for (int off = 128; off > 0; off >>= 1) {
    if (t < off) {
      #pragma unroll
      for (int s = 0; s < 21; ++s) red[t][s] += red[t+off][s];
    }
    __syncthreads();
  }
  if (t < 21) wsf[WS_P1 + b*24 + t] = red[0][t];

  // one k-row of W2 (blocks 0-255) / W3 (blocks 256-511) -> bf16 transposed
  if (b < 256) {
    ((ushort*)(wsf + WS_W2T))[t*256 + b] = f2bf(W2[b*256 + t]);
  } else {
    const int bb = b - 256;
    ((ushort*)(wsf + WS_W3T))[t*256 + bb] = f2bf(W3[bb*256 + t]);
  }
}

// ---- finalize1: parallel reduce of 512 partials + layer-1 BN fold ----
__global__ __launch_bounds__(256) void finalize1_kernel(
    const float* __restrict__ part, const float* __restrict__ W1,
    const float* __restrict__ b1, const float* __restrict__ g1,
    const float* __restrict__ be1, float* __restrict__ wsf) {
  __shared__ float red[256][22];
  __shared__ float sarr[21];
  const int t = threadIdx.x;
  #pragma unroll
  for (int s = 0; s < 21; ++s)
    red[t][s] = part[t*24 + s] + part[(t+256)*24 + s];
  __syncthreads();
  for (int off = 128; off > 0; off >>= 1) {
    if (t < off) {
      #pragma unroll
      for (int s = 0; s < 21; ++s) red[t][s] += red[t+off][s];
    }
    __syncthreads();
  }
  if (t < 21) sarr[t] = red[0][t];
  __syncthreads();
  float s[21];
  #pragma unroll
  for (int i = 0; i < 21; ++i) s[i] = sarr[i];
  const float cnt = fmaxf(s[0], 1.f);
  float w[4] = {W1[t], W1[256+t], W1[512+t], W1[768+t]};
  const float b1f = b1[t];
  float sw = 0.f;
  #pragma unroll
  for (int k = 0; k < 4; ++k) sw = fmaf(s[1+k], w[k], sw);
  float qf = 0.f;
  #pragma unroll
  for (int i = 0; i < 4; ++i)
    #pragma unroll
    for (int j = 0; j < 4; ++j) qf = fmaf(s[5+i*4+j]*w[i], w[j], qf);
  const float mu  = sw/cnt + b1f;
  const float eh2 = (qf + 2.f*b1f*sw)/cnt + b1f*b1f;
  const float var = fmaxf(eh2 - mu*mu, 0.f);
  const float a1  = g1[t] * rsqrtf(var + BN_EPS_F);
  const float c1  = be1[t] - mu*a1;
  #pragma unroll
  for (int k = 0; k < 4; ++k) wsf[WS_A1 + k*256 + t] = w[k]*a1;
  wsf[WS_D1 + t] = fmaf(b1f, a1, c1);
  if (t == 0) wsf[WS_CNT] = cnt;
}

// ---- stats2: h1 -> GEMM2 (B2 regs) -> masked sum/sq partials (2 w/SIMD) ----
__global__ __launch_bounds__(256, 2) void stats2_mfma(
    const float* __restrict__ bbox, const void* __restrict__ maskp,
    const float* wsf, const float* __restrict__ b2,
    float* __restrict__ part2) {
  __shared__ float xs[64][4];
  __shared__ float ms[64];
  __shared__ ushort h1s[64*256];
  __shared__ int s_fmt;
  const int t = threadIdx.x, lane = t & 63, wave = t >> 6;
  if (t == 0) s_fmt = 0;
  __syncthreads();
  {
    const uint4 v = ((const uint4*)maskp)[t];
    if (((v.x | v.y | v.z | v.w) & 0xFFFFFF00u) != 0u) s_fmt = 1;
  }
  __syncthreads();
  const int fmt = s_fmt;
  float a1c[4][2], d1c[2];
  {
    const int c0 = (t & 127) * 2;
    #pragma unroll
    for (int j = 0; j < 4; ++j) {
      a1c[j][0] = wsf[WS_A1 + j*256 + c0];
      a1c[j][1] = wsf[WS_A1 + j*256 + c0 + 1];
    }
    d1c[0] = wsf[WS_D1 + c0]; d1c[1] = wsf[WS_D1 + c0 + 1];
  }
  short8 B2r[4][8];
  load_B((const ushort*)(wsf + WS_W2T), lane, wave, B2r);
  float b2v[4];
  #pragma unroll
  for (int cf = 0; cf < 4; ++cf) b2v[cf] = b2[wave*64 + cf*16 + (lane & 15)];
  float pS[4] = {0,0,0,0}, pQ[4] = {0,0,0,0};

  for (int tile = blockIdx.x; tile < NTILES; tile += GRID_STATS) {
    const int row0 = tile << 6;
    __syncthreads();
    if (t < 64) {
      float4 x4 = *(const float4*)(bbox + (size_t)(row0 + t) * 16);
      xs[t][0] = x4.x; xs[t][1] = x4.y; xs[t][2] = x4.z; xs[t][3] = x4.w;
      ms[t] = load_mask(maskp, fmt, row0 + t);
    }
    __syncthreads();
    compute_h1(xs, h1s, t, a1c, d1c);
    __syncthreads();
    f32x4 acc[4][4];
    #pragma unroll
    for (int rf = 0; rf < 4; ++rf)
      #pragma unroll
      for (int cf = 0; cf < 4; ++cf)
        acc[rf][cf] = (f32x4){b2v[cf], b2v[cf], b2v[cf], b2v[cf]};
    gemm_reg(h1s, B2r, lane, acc);
    float mr[4][4];
    #pragma unroll
    for (int rf = 0; rf < 4; ++rf)
      #pragma unroll
      for (int r = 0; r < 4; ++r)
        mr[rf][r] = ms[rf*16 + ((lane >> 4) * 4) + r];
    #pragma unroll
    for (int cf = 0; cf < 4; ++cf)
      #pragma unroll
      for (int rf = 0; rf < 4; ++rf)
        #pragma unroll
        for (int r = 0; r < 4; ++r) {
          const float m = mr[rf][r];
          const float v = acc[rf][cf][r];
          pS[cf] = fmaf(m, v, pS[cf]);
          pQ[cf] = fmaf(m*v, v, pQ[cf]);
        }
  }
  #pragma unroll
  for (int cf = 0; cf < 4; ++cf) {
    pS[cf] += __shfl_xor(pS[cf], 16); pS[cf] += __shfl_xor(pS[cf], 32);
    pQ[cf] += __shfl_xor(pQ[cf], 16); pQ[cf] += __shfl_xor(pQ[cf], 32);
  }
  if (lane < 16) {
    #pragma unroll
    for (int cf = 0; cf < 4; ++cf) {
      const int col = wave*64 + cf*16 + lane;
      part2[(size_t)blockIdx.x*512 + col] = pS[cf];
      part2[(size_t)blockIdx.x*512 + 256 + col] = pQ[cf];
    }
  }
}

// ---- finalize2: one block per feature -> a2/c2 ----
__global__ __launch_bounds__(256) void finalize2_kernel(
    float* __restrict__ wsf, const float* __restrict__ g2,
    const float* __restrict__ be2) {
  const int f = blockIdx.x, t = threadIdx.x;
  const float* part2 = wsf + WS_P2;
  float s1 = 0.f, s2 = 0.f;
  for (int b = t; b < GRID_STATS; b += 256) {
    s1 += part2[(size_t)b*512 + f];
    s2 += part2[(size_t)b*512 + 256 + f];
  }
  __shared__ float r1[256], r2[256];
  r1[t] = s1; r2[t] = s2;
  __syncthreads();
  for (int off = 128; off > 0; off >>= 1) {
    if (t < off) { r1[t] += r1[t+off]; r2[t] += r2[t+off]; }
    __syncthreads();
  }
  if (t == 0) {
    const float cnt = wsf[WS_CNT];
    const float mu  = r1[0]/cnt;
    const float var = fmaxf(r2[0]/cnt - mu*mu, 0.f);
    const float a2  = g2[f] * rsqrtf(var + BN_EPS_F);
    wsf[WS_A2 + f] = a2;
    wsf[WS_C2 + f] = be2[f] - mu*a2;
  }
}

// ---- mlp3: 256 threads, 4 waves x 64 cols, B2+B3 in regs, 1 wave/SIMD ----
// (r10-proven configuration — the structural local optimum, reproduced at
//  205.4/205.7 µs. All eight variants lost: 512-thread shapes spill at a
//  128-VGPR cap; staging/specialization/barrier-thinning each cost more
//  than the serialization they removed.)
__global__ __launch_bounds__(256, 1) void mlp3_mfma(
    const float* __restrict__ bbox, const void* __restrict__ maskp,
    const float* wsf, const float* __restrict__ b2,
    const float* __restrict__ b3, float* __restrict__ out) {
  __shared__ ushort h1s[64*256];       // 32 KB
  __shared__ float xst[ROWS_MLP][4];   // 16 KB
  __shared__ float mst[ROWS_MLP];      // 4 KB
  __shared__ int s_fmt;
  const int t = threadIdx.x, lane = t & 63, wave = t >> 6;
  if (t == 0) s_fmt = 0;
  __syncthreads();
  {
    const uint4 v = ((const uint4*)maskp)[t];
    if (((v.x | v.y | v.z | v.w) & 0xFFFFFF00u) != 0u) s_fmt = 1;
  }
  __syncthreads();
  const int fmt = s_fmt;
  const int row_base = blockIdx.x * ROWS_MLP;

  #pragma unroll
  for (int i = 0; i < ROWS_MLP/256; ++i) {
    const int r = i*256 + t;
    float4 x4 = *(const float4*)(bbox + (size_t)(row_base + r) * 16);
    xst[r][0] = x4.x; xst[r][1] = x4.y; xst[r][2] = x4.z; xst[r][3] = x4.w;
    mst[r] = load_mask(maskp, fmt, row_base + r);
  }
  float a1c[4][2], d1c[2];
  {
    const int c0 = (t & 127) * 2;
    #pragma unroll
    for (int j = 0; j < 4; ++j) {
      a1c[j][0] = wsf[WS_A1 + j*256 + c0];
      a1c[j][1] = wsf[WS_A1 + j*256 + c0 + 1];
    }
    d1c[0] = wsf[WS_D1 + c0]; d1c[1] = wsf[WS_D1 + c0 + 1];
  }
  short8 B2r[4][8], B3r[4][8];
  load_B((const ushort*)(wsf + WS_W2T), lane, wave, B2r);
  load_B((const ushort*)(wsf + WS_W3T), lane, wave, B3r);
  float b2v[4], b3v[4], a2v[4], c2v[4];
  #pragma unroll
  for (int cf = 0; cf < 4; ++cf) {
    const int col = wave*64 + cf*16 + (lane & 15);
    b2v[cf] = b2[col]; b3v[cf] = b3[col];
    a2v[cf] = wsf[WS_A2 + col]; c2v[cf] = wsf[WS_C2 + col];
  }
  __syncthreads();

  for (int tile = 0; tile < TILES_MLP; ++tile) {
    const int r0 = tile * 64;
    compute_h1(&xst[r0], h1s, t, a1c, d1c);
    barrier_lds();
    f32x4 acc[4][4];
    #pragma unroll
    for (int rf = 0; rf < 4; ++rf)
      #pragma unroll
      for (int cf = 0; cf < 4; ++cf)
        acc[rf][cf] = (f32x4){b2v[cf], b2v[cf], b2v[cf], b2v[cf]};
    gemm_reg(h1s, B2r, lane, acc);
    barrier_lds();   // all waves done reading h1s -> safe to overwrite
    #pragma unroll
    for (int rf = 0; rf < 4; ++rf)
      #pragma unroll
      for (int cf = 0; cf < 4; ++cf) {
        const int col = wave*64 + cf*16 + (lane & 15);
        #pragma unroll
        for (int r = 0; r < 4; ++r) {
          const float v = fmaxf(fmaf(acc[rf][cf][r], a2v[cf], c2v[cf]), 0.f);
          const int row = rf*16 + ((lane >> 4) * 4) + r;
          unsigned int byte = (unsigned int)row*512u + (unsigned int)col*2u;
          byte ^= (unsigned int)(row & 7) << 4;
          *(ushort*)((char*)h1s + byte) = f2bf(v);
        }
      }
    barrier_lds();
    #pragma unroll
    for (int rf = 0; rf < 4; ++rf)
      #pragma unroll
      for (int cf = 0; cf < 4; ++cf)
        acc[rf][cf] = (f32x4){b3v[cf], b3v[cf], b3v[cf], b3v[cf]};
    gemm_reg(h1s, B3r, lane, acc);
    float mr[4][4];
    #pragma unroll
    for (int rf = 0; rf < 4; ++rf)
      #pragma unroll
      for (int r = 0; r < 4; ++r)
        mr[rf][r] = mst[r0 + rf*16 + ((lane >> 4) * 4) + r];
    #pragma unroll
    for (int rf = 0; rf < 4; ++rf)
      #pragma unroll
      for (int cf = 0; cf < 4; ++cf) {
        const int col = wave*64 + cf*16 + (lane & 15);
        #pragma unroll
        for (int r = 0; r < 4; ++r) {
          const int lrow = rf*16 + ((lane >> 4) * 4) + r;
          out[(size_t)(row_base + r0 + lrow)*256 + col] =
              acc[rf][cf][r] * mr[rf][r];
        }
      }
    barrier_lds();   // gemm3/mst reads done -> next tile may write h1s
  }
}

extern "C" void kernel_launch(void* const* d_in, const int* in_sizes, int n_in,
                              void* d_out, int out_size, void* d_ws, size_t ws_size,
                              hipStream_t stream) {
  (void)in_sizes; (void)n_in; (void)out_size; (void)ws_size;
  const float* bbox = (const float*)d_in[0];
  const void*  maskp= d_in[1];
  const float* W1 = (const float*)d_in[2];
  const float* b1 = (const float*)d_in[3];
  const float* g1 = (const float*)d_in[4];
  const float* be1= (const float*)d_in[5];
  const float* W2 = (const float*)d_in[6];
  const float* b2 = (const float*)d_in[7];
  const float* g2 = (const float*)d_in[8];
  const float* be2= (const float*)d_in[9];
  const float* W3 = (const float*)d_in[10];
  const float* b3 = (const float*)d_in[11];
  float* out = (float*)d_out;
  float* wsf = (float*)d_ws;

  hipLaunchKernelGGL(setup_kernel, dim3(GRID_SETUP), dim3(256), 0, stream,
                     bbox, maskp, W2, W3, wsf);
  hipLaunchKernelGGL(finalize1_kernel, dim3(1), dim3(256), 0, stream,
                     wsf + WS_P1, W1, b1, g1, be1, wsf);
  hipLaunchKernelGGL(stats2_mfma, dim3(GRID_STATS), dim3(256), 0, stream,
                     bbox, maskp, wsf, b2, wsf + WS_P2);
  hipLaunchKernelGGL(finalize2_kernel, dim3(256), dim3(256), 0, stream,
                     wsf, g2, be2);
  hipLaunchKernelGGL(mlp3_mfma, dim3(GRID_MLP), dim3(256), 0, stream,
                     bbox, maskp, wsf, b2, b3, out);
}